// Round 4
// baseline (1919.821 us; speedup 1.0000x reference)
//
#include <hip/hip_runtime.h>
#include <stdint.h>

// ---------------- problem constants ----------------
#define EDIM   300      // hidden/embed dim
#define EPAD   304      // padded to 8*38 for recurrence dot
#define KPAD   320      // padded K for MFMA GEMMs
#define NG     1200     // 4*EDIM gates
#define NB     64       // batch
#define SENC   64       // encoder steps
#define SDEC   63       // decoder steps
#define ZHV    12016
#define DROWS  4032     // NB*SDEC
#define MPAD   4096

typedef unsigned short u16;
typedef __attribute__((ext_vector_type(8))) short bf16x8;
typedef __attribute__((ext_vector_type(4))) float f32x4;
typedef __attribute__((ext_vector_type(2))) _Float16 f16x2;

static __device__ __forceinline__ u16 f2bf(float f){
  uint32_t u = __builtin_bit_cast(uint32_t, f);
  return (u16)((u + 0x7fffu + ((u >> 16) & 1u)) >> 16);
}
static __device__ __forceinline__ u16 f2h(float f){
  return __builtin_bit_cast(u16, (_Float16)f);
}
static __device__ __forceinline__ float sigm(float x){ return 1.f/(1.f + __expf(-x)); }
static __device__ __forceinline__ float tanhf_(float x){
  x = fminf(fmaxf(x, -15.f), 15.f);
  float e = __expf(2.f*x);
  return (e - 1.f)/(e + 1.f);
}

// 2-way fp16 dot: acc += w.lo*h.lo + w.hi*h.hi  (v_dot2_f32_f16 when available)
#if __has_builtin(__builtin_amdgcn_fdot2)
static __device__ __forceinline__ float dot2(uint32_t w, uint32_t h, float acc){
  return __builtin_amdgcn_fdot2(__builtin_bit_cast(f16x2, w),
                                __builtin_bit_cast(f16x2, h), acc, false);
}
#else
static __device__ __forceinline__ float dot2(uint32_t w, uint32_t h, float acc){
  f16x2 wv = __builtin_bit_cast(f16x2, w), hv = __builtin_bit_cast(f16x2, h);
  acc = fmaf((float)wv[0], (float)hv[0], acc);
  acc = fmaf((float)wv[1], (float)hv[1], acc);
  return acc;
}
#endif

// ---------------- workspace init ----------------
__global__ void zero_kernel(float4* p, long n){
  long i = (long)blockIdx.x*blockDim.x + threadIdx.x;
  long st = (long)gridDim.x*blockDim.x;
  float4 z = {0.f,0.f,0.f,0.f};
  for (; i < n; i += st) p[i] = z;
}

// ---------------- weight repack: Whh (1200x300) f32 -> wave-tiled fp16 ----------------
// uint4 chunk index ((g*38 + kc)*64 + jl); g = G*5 + w, output j = G*300 + w*64 + jl,
// chunk holds k = kc*8 .. kc*8+7 (zero-padded past 300).
__global__ void build_whh(const float* __restrict__ W, u16* __restrict__ out){
  int idx = blockIdx.x*blockDim.x + threadIdx.x;
  if (idx >= 20*38*64) return;
  int jl = idx & 63;
  int kc = (idx >> 6) % 38;
  int g  = (idx >> 6) / 38;
  int G = g/5, w = g - G*5;
  int jg = w*64 + jl;
  union { u16 u[8]; uint4 q; } v;
  for (int e=0;e<8;e++){
    int k = kc*8+e;
    float f = (jg < EDIM && k < EDIM) ? W[(size_t)(G*EDIM + jg)*EDIM + k] : 0.f;
    v.u[e] = f2h(f);
  }
  ((uint4*)out)[idx] = v.q;
}

// ---------------- weight repack: (N x 300) f32 -> (Npad x 320) bf16 ----------------
__global__ void build_b(const float* __restrict__ W, u16* __restrict__ out, int N){
  int idx = blockIdx.x*blockDim.x + threadIdx.x;
  if (idx >= N*EDIM) return;
  int n = idx / EDIM, k = idx - n*EDIM;
  out[(size_t)n*KPAD + k] = f2bf(W[idx]);
}

// ---------------- embeddings -> padded bf16 A operands ----------------
__global__ void embed_en(const int* __restrict__ ids, const float* __restrict__ emb, u16* __restrict__ x){
  int idx = blockIdx.x*blockDim.x + threadIdx.x;
  if (idx >= MPAD*EDIM) return;
  int r = idx / EDIM, k = idx - r*EDIM;
  x[(size_t)r*KPAD + k] = f2bf(emb[(size_t)ids[r]*EDIM + k]);
}
__global__ void embed_zh(const int* __restrict__ zh, const float* __restrict__ emb, u16* __restrict__ x){
  int idx = blockIdx.x*blockDim.x + threadIdx.x;
  if (idx >= DROWS*EDIM) return;
  int r = idx / EDIM, k = idx - r*EDIM;
  int b = r / SDEC, t = r - b*SDEC;
  x[(size_t)r*KPAD + k] = f2bf(emb[(size_t)zh[b*SENC + t]*EDIM + k]);
}

// ---------------- bf16 MFMA GEMM: C[m,n] = sum_k A[m,k]*B[n,k] (+bias[n]) ----------------
#define LDT 40   // LDS row stride in bf16 elems (80 B)
__global__ __launch_bounds__(256) void gemm_nt(const u16* __restrict__ A, const u16* __restrict__ B,
                float* __restrict__ C, int ldc, int Mreal, int Nreal, const float* __restrict__ bias){
  __shared__ __align__(16) u16 As[128*LDT];
  __shared__ __align__(16) u16 Bs[128*LDT];
  int tid = threadIdx.x;
  int lane = tid & 63, wave = tid >> 6;
  int wm = wave >> 1, wn = wave & 1;
  int m0 = blockIdx.y*128, n0 = blockIdx.x*128;
  f32x4 acc[4][4];
  for (int i=0;i<4;i++) for (int j=0;j<4;j++) acc[i][j] = (f32x4){0.f,0.f,0.f,0.f};
  int r16 = lane & 15, kg = lane >> 4;
  for (int kt=0; kt<KPAD/32; kt++){
    int k0 = kt*32;
    for (int c=0;c<2;c++){
      int id = c*256 + tid;            // 0..511
      int row = id >> 2, col = id & 3; // 4 x 16B chunks per 32-k row
      *(uint4*)&As[row*LDT + col*8] = *(const uint4*)&A[(size_t)(m0+row)*KPAD + k0 + col*8];
      *(uint4*)&Bs[row*LDT + col*8] = *(const uint4*)&B[(size_t)(n0+row)*KPAD + k0 + col*8];
    }
    __syncthreads();
    bf16x8 af[4], bfr[4];
    for (int i=0;i<4;i++) af[i]  = *(const bf16x8*)&As[(wm*64 + i*16 + r16)*LDT + kg*8];
    for (int j=0;j<4;j++) bfr[j] = *(const bf16x8*)&Bs[(wn*64 + j*16 + r16)*LDT + kg*8];
    for (int i=0;i<4;i++)
      for (int j=0;j<4;j++)
        acc[i][j] = __builtin_amdgcn_mfma_f32_16x16x32_bf16(af[i], bfr[j], acc[i][j], 0, 0, 0);
    __syncthreads();
  }
  // C/D layout (m89-verified): col = lane&15, row = (lane>>4)*4 + reg
  for (int j=0;j<4;j++){
    int col = n0 + wn*64 + j*16 + r16;
    if (col >= Nreal) continue;
    float bv = bias ? bias[col] : 0.f;
    for (int i=0;i<4;i++){
      int rbase = m0 + wm*64 + i*16 + kg*4;
      for (int r=0;r<4;r++){
        int row = rbase + r;
        if (row < Mreal) C[(size_t)row*ldc + col] = acc[i][j][r] + bv;
      }
    }
  }
}

// ---------------- LSTM recurrence: one block per batch row ----------------
// 64 blocks x 640 threads. Wave wv owns g-groups {2wv, 2wv+1} (each 64 outputs
// of the 1280-padded gate vector). All 1200 gates computed in-block; gates and
// h exchanged through LDS with two __syncthreads per step — ZERO cross-block
// communication. Weights streamed from per-XCD L2 (8 blocks/XCD share the
// resident 778 KB copy). h kept as packed fp16 in LDS; dot via v_dot2_f32_f16
// (2 MAC/inst, no unpack). LDS h reads are wave-uniform -> conflict-free
// broadcast.
__global__ __launch_bounds__(640) void recur_row(
    const float* __restrict__ Xih, const u16* __restrict__ Wt,
    const float* __restrict__ bias, const float* __restrict__ h0,
    const float* __restrict__ c0,
    u16* seq, float* hfin, float* cfin, int steps)
{
  int r = blockIdx.x;
  int tid = threadIdx.x;
  int wv = tid >> 6, jl = tid & 63;
  int gA = 2*wv, gB = 2*wv + 1;
  int GA = gA/5, wA = gA - GA*5;
  int GB = gB/5, wB = gB - GB*5;
  bool actA = (wA*64 + jl) < EDIM;
  bool actB = (wB*64 + jl) < EDIM;
  int jA = GA*EDIM + wA*64 + jl;
  int jB = GB*EDIM + wB*64 + jl;
  const uint4* wt4 = (const uint4*)Wt;
  const uint4* wpA = wt4 + (size_t)gA*38*64 + jl;
  const uint4* wpB = wt4 + (size_t)gB*38*64 + jl;
  float bA = actA ? bias[jA] : 0.f;
  float bB = actB ? bias[jB] : 0.f;

  __shared__ __align__(16) u16 h16[EPAD];   // fp16 hidden state
  __shared__ float g_lds[NG];               // gate exchange

  float c_reg = 0.f;
  if (tid < EDIM){
    c_reg = c0[r*EDIM + tid];
    h16[tid] = f2h(h0[r*EDIM + tid]);
  } else if (tid < EPAD) h16[tid] = 0;
  __syncthreads();

  const uint4* h4 = (const uint4*)h16;
  for (int t=0; t<steps; t++){
    float xA = actA ? Xih[(size_t)(r*steps + t)*NG + jA] : 0.f;
    float xB = actB ? Xih[(size_t)(r*steps + t)*NG + jB] : 0.f;
    float aA = 0.f, aB = 0.f;
    #pragma unroll 2
    for (int kc=0; kc<38; kc++){
      uint4 hv = h4[kc];          // broadcast (same addr across wave)
      uint4 wa = wpA[kc<<6];
      uint4 wb = wpB[kc<<6];
      aA = dot2(wa.x, hv.x, aA);
      aA = dot2(wa.y, hv.y, aA);
      aA = dot2(wa.z, hv.z, aA);
      aA = dot2(wa.w, hv.w, aA);
      aB = dot2(wb.x, hv.x, aB);
      aB = dot2(wb.y, hv.y, aB);
      aB = dot2(wb.z, hv.z, aB);
      aB = dot2(wb.w, hv.w, aB);
    }
    if (actA) g_lds[jA] = bA + xA + aA;
    if (actB) g_lds[jB] = bB + xB + aB;
    __syncthreads();              // gates ready; h reads of this step done
    if (tid < EDIM){
      float gi = g_lds[tid];
      float gf = g_lds[EDIM   + tid];
      float gg = g_lds[2*EDIM + tid];
      float go = g_lds[3*EDIM + tid];
      c_reg = sigm(gf)*c_reg + sigm(gi)*tanhf_(gg);
      float hv = sigm(go)*tanhf_(c_reg);
      h16[tid] = f2h(hv);
      if (seq) seq[(size_t)(r*steps + t)*KPAD + tid] = f2bf(hv);
      if (t == steps-1 && hfin){ hfin[r*EDIM + tid] = hv; cfin[r*EDIM + tid] = c_reg; }
    }
    __syncthreads();              // h(t) complete before next dot / g_lds reuse
  }
}

// ---------------- fused log_softmax (in-place on d_out) + masked NLL ----------------
__global__ __launch_bounds__(256) void lsm_loss(float* __restrict__ out, const int* __restrict__ zh,
                                                float* __restrict__ lacc){
  int row = blockIdx.x;
  int tid = threadIdx.x;
  __shared__ float buf[ZHV];
  __shared__ float red[8];
  float* p = out + (size_t)row*ZHV;
  float m = -1e30f;
  for (int i=tid; i<ZHV; i+=256){ float v = p[i]; buf[i] = v; m = fmaxf(m, v); }
  for (int off=32; off; off>>=1) m = fmaxf(m, __shfl_xor(m, off));
  if ((tid&63)==0) red[tid>>6] = m;
  __syncthreads();
  m = fmaxf(fmaxf(red[0],red[1]), fmaxf(red[2],red[3]));
  float s = 0.f;
  for (int i=tid; i<ZHV; i+=256) s += __expf(buf[i]-m);
  for (int off=32; off; off>>=1) s += __shfl_xor(s, off);
  if ((tid&63)==0) red[4+(tid>>6)] = s;
  __syncthreads();
  s = red[4]+red[5]+red[6]+red[7];
  float lse = m + __logf(s);
  for (int i=tid; i<ZHV; i+=256) p[i] = buf[i] - lse;
  if (tid == 0){
    int b = row / SDEC, t = row - b*SDEC;
    int tgt = zh[b*SENC + t + 1];
    if (tgt != 0){
      atomicAdd(&lacc[0], -(buf[tgt] - lse));
      atomicAdd(&lacc[1], 1.0f);
    }
  }
}

__global__ void fin_loss(float* out, const float* lacc){
  out[(size_t)DROWS*ZHV] = lacc[0]/lacc[1];
}

// ---------------- host ----------------
extern "C" void kernel_launch(void* const* d_in, const int* in_sizes, int n_in,
                              void* d_out, int out_size, void* d_ws, size_t ws_size,
                              hipStream_t stream){
  const int*   en_in   = (const int*)d_in[0];
  const int*   zh_in   = (const int*)d_in[1];
  const float* en_emb  = (const float*)d_in[2];
  const float* zh_emb  = (const float*)d_in[3];
  const float* enc_Wih = (const float*)d_in[4];
  const float* enc_Whh = (const float*)d_in[5];
  const float* enc_b   = (const float*)d_in[6];
  const float* dec_Wih = (const float*)d_in[7];
  const float* dec_Whh = (const float*)d_in[8];
  const float* dec_b   = (const float*)d_in[9];
  const float* fc_W    = (const float*)d_in[10];
  const float* fc_b    = (const float*)d_in[11];
  float* out = (float*)d_out;
  char* ws = (char*)d_ws;

  size_t o = 0;
  auto alloc = [&](size_t b){ size_t r = o; o = (o + b + 255) & ~(size_t)255; return r; };
  size_t whh[4], wih[4];
  for (int i=0;i<4;i++) whh[i] = alloc((size_t)20*38*64*8*2);   // wave-tiled Whh fp16
  for (int i=0;i<4;i++) wih[i] = alloc((size_t)1280*KPAD*2);    // Wih as B operand
  size_t fcw  = alloc((size_t)12032*KPAD*2);
  size_t xen  = alloc((size_t)MPAD*KPAD*2);
  size_t xl1e = alloc((size_t)MPAD*KPAD*2);
  size_t xzh  = alloc((size_t)MPAD*KPAD*2);
  size_t xl1d = alloc((size_t)MPAD*KPAD*2);
  size_t xl2d = alloc((size_t)MPAD*KPAD*2);
  size_t xih  = alloc((size_t)MPAD*NG*4);
  size_t hfin = alloc((size_t)2*NB*EDIM*4);
  size_t cfin = alloc((size_t)2*NB*EDIM*4);
  size_t hz   = alloc((size_t)NB*EDIM*4);
  size_t lac  = alloc(256);
  size_t used = o;
  if (ws_size < used) return;  // fail loudly (output stays poisoned)

  zero_kernel<<<2048,256,0,stream>>>((float4*)ws, (long)(used/16));

  for (int l=0;l<2;l++){
    build_whh<<<190,256,0,stream>>>(enc_Whh + (size_t)l*NG*EDIM, (u16*)(ws+whh[l]));
    build_whh<<<190,256,0,stream>>>(dec_Whh + (size_t)l*NG*EDIM, (u16*)(ws+whh[2+l]));
    build_b<<<1407,256,0,stream>>>(enc_Wih + (size_t)l*NG*EDIM, (u16*)(ws+wih[l]),   NG);
    build_b<<<1407,256,0,stream>>>(dec_Wih + (size_t)l*NG*EDIM, (u16*)(ws+wih[2+l]), NG);
  }
  build_b<<<(ZHV*EDIM+255)/256,256,0,stream>>>(fc_W, (u16*)(ws+fcw), ZHV);
  embed_en<<<(MPAD*EDIM+255)/256,256,0,stream>>>(en_in, en_emb, (u16*)(ws+xen));
  embed_zh<<<(DROWS*EDIM+255)/256,256,0,stream>>>(zh_in, zh_emb, (u16*)(ws+xzh));

  float* XIH = (float*)(ws+xih);
  float* LAC = (float*)(ws+lac);
  float* HF  = (float*)(ws+hfin);
  float* CF  = (float*)(ws+cfin);
  float* HZ  = (float*)(ws+hz);

  // encoder layer 1
  gemm_nt<<<dim3(10,32),256,0,stream>>>((u16*)(ws+xen), (u16*)(ws+wih[0]), XIH, NG, MPAD, NG, nullptr);
  recur_row<<<64,640,0,stream>>>(XIH, (u16*)(ws+whh[0]), enc_b, HZ, HZ, (u16*)(ws+xl1e), HF, CF, SENC);
  // encoder layer 2 (hidden sequence unused; only finals kept)
  gemm_nt<<<dim3(10,32),256,0,stream>>>((u16*)(ws+xl1e), (u16*)(ws+wih[1]), XIH, NG, MPAD, NG, nullptr);
  recur_row<<<64,640,0,stream>>>(XIH, (u16*)(ws+whh[1]), enc_b+NG, HZ, HZ, nullptr, HF+NB*EDIM, CF+NB*EDIM, SENC);
  // decoder layer 1
  gemm_nt<<<dim3(10,32),256,0,stream>>>((u16*)(ws+xzh), (u16*)(ws+wih[2]), XIH, NG, MPAD, NG, nullptr);
  recur_row<<<64,640,0,stream>>>(XIH, (u16*)(ws+whh[2]), dec_b, HF, CF, (u16*)(ws+xl1d), nullptr, nullptr, SDEC);
  // decoder layer 2
  gemm_nt<<<dim3(10,32),256,0,stream>>>((u16*)(ws+xl1d), (u16*)(ws+wih[3]), XIH, NG, MPAD, NG, nullptr);
  recur_row<<<64,640,0,stream>>>(XIH, (u16*)(ws+whh[3]), dec_b+NG, HF+NB*EDIM, CF+NB*EDIM, (u16*)(ws+xl2d), nullptr, nullptr, SDEC);
  // FC head -> logits straight into d_out
  gemm_nt<<<dim3(94,32),256,0,stream>>>((u16*)(ws+xl2d), (u16*)(ws+fcw), out, ZHV, DROWS, ZHV, fc_b);
  // in-place log_softmax + masked NLL
  lsm_loss<<<DROWS,256,0,stream>>>(out, zh_in, LAC);
  fin_loss<<<1,1,0,stream>>>(out, LAC);
}